// Round 4
// baseline (87.834 us; speedup 1.0000x reference)
//
#include <hip/hip_runtime.h>

#define CH    128
#define HH    56
#define WW    56
#define BB    32
#define NPIX  (BB * HH * WW)   // 100352
#define NSLOT 32
#define PW    58               // padded row width (1 zero col each side)
#define PROW  (PW * PW)        // padded per-batch: 58 rows x 58 cols = 3364

struct alignas(16) U2 { unsigned long long x, y; };

// ---------------- pack x signs into zero-padded layout ----------------
// xbp[b][h+1][w+1]; border rows/cols stay zero (memset before this kernel).
// bit l of word0 = sign(x[ch 2l]); bit l of word1 = sign(x[ch 2l+1]).
__global__ __launch_bounds__(256) void pack_x_k(const float* __restrict__ x, U2* __restrict__ xbp) {
    int wave = threadIdx.x >> 6;
    int lane = threadIdx.x & 63;
    int p = blockIdx.x * 4 + wave;           // grid = NPIX/4 exactly
    const float2* px = (const float2*)(x + (size_t)p * CH);
    float2 v = px[lane];
    unsigned long long b0 = __ballot(v.x >= 0.0f);
    unsigned long long b1 = __ballot(v.y >= 0.0f);
    if (lane == 0) {
        int w = p % WW;
        int t = p / WW;
        int h = t % HH;
        int b = t / HH;
        U2 o; o.x = b0; o.y = b1;
        xbp[(size_t)b * PROW + (size_t)(h + 1) * PW + (w + 1)] = o;
    }
}

// ---------------- pack W signs (+ zero accum slots) ----------------
// W is HWIO: W[kh][kw][ci][co]; even/odd ci split matches pack_x.
__global__ __launch_bounds__(128) void pack_w_k(const float* __restrict__ Wt, U2* __restrict__ wb,
                                                unsigned long long* __restrict__ accum) {
    int tap = blockIdx.x;     // 0..8
    int co  = threadIdx.x;    // 0..127
    for (int k = tap * 128 + co; k < NSLOT * 256; k += 9 * 128) accum[k] = 0ull;
    const float* base = Wt + (size_t)tap * CH * CH + co;
    unsigned long long b0 = 0, b1 = 0;
    #pragma unroll 4
    for (int ci = 0; ci < 64; ++ci) {
        if (base[(size_t)(2 * ci)     * CH] >= 0.0f) b0 |= 1ull << ci;
        if (base[(size_t)(2 * ci + 1) * CH] >= 0.0f) b1 |= 1ull << ci;
    }
    wb[tap * CH + co].x = b0;
    wb[tap * CH + co].y = b1;
}

// ---------------- conv + stats (stores r as u16) ----------------
// Block = (h, b). 256 threads: c = tid&127, g = tid>>7 (column half, 28 cols).
// Window is wave-uniform -> scalar loads from padded xbp; weights per-lane in VGPRs.
template<bool STORE_R>
__global__ __launch_bounds__(256) void conv_stats_k(const U2* __restrict__ xbp,
                                                    const U2* __restrict__ wbg,
                                                    unsigned long long* __restrict__ accum,
                                                    unsigned short* __restrict__ rb) {
    int h = blockIdx.x;       // 0..55
    int b = blockIdx.y;       // 0..31
    int tid = threadIdx.x;
    int c = tid & (CH - 1);
    int g = tid >> 7;

    // per-thread weights + padding corrections (corr[t] = 128 - 2*popc(wb[t]))
    U2 wb[3][3];
    int corr[3][3];
    #pragma unroll
    for (int r = 0; r < 3; ++r)
        #pragma unroll
        for (int k = 0; k < 3; ++k) {
            U2 wv = wbg[(r * 3 + k) * CH + c];
            wb[r][k] = wv;
            corr[r][k] = CH - 2 * (__popcll(wv.x) + __popcll(wv.y));
        }
    bool v0 = (h > 0), v2 = (h < HH - 1);
    int corrR = 0, ccol0 = corr[1][0], ccol2 = corr[1][2];
    if (!v0) corrR += corr[0][0] + corr[0][1] + corr[0][2];
    else     { ccol0 += corr[0][0]; ccol2 += corr[0][2]; }
    if (!v2) corrR += corr[2][0] + corr[2][1] + corr[2][2];
    else     { ccol0 += corr[2][0]; ccol2 += corr[2][2]; }
    int base0 = 9 * CH - corrR;

    int w0 = g * 28;
    // padded row pointers: image row (h-1+r) -> padded row (h+r); image col (w0-1) -> padded col w0
    const U2* r0 = xbp + (size_t)b * PROW + (size_t)h * PW + w0;
    const U2* r1 = r0 + PW;
    const U2* r2 = r1 + PW;

    U2 A0 = r0[0], A1 = r1[0], A2 = r2[0];
    U2 B0 = r0[1], B1 = r1[1], B2 = r2[1];

    unsigned int s1 = 0, s2 = 0;
    unsigned short* rout = rb + ((((size_t)b * HH + h) * WW) + w0) * CH + c;

    #pragma unroll
    for (int i = 0; i < 28; ++i) {
        U2 C0 = r0[i + 2], C1 = r1[i + 2], C2 = r2[i + 2];
        int m0 = __popcll(A0.x ^ wb[0][0].x) + __popcll(A0.y ^ wb[0][0].y)
               + __popcll(B0.x ^ wb[0][1].x) + __popcll(B0.y ^ wb[0][1].y)
               + __popcll(C0.x ^ wb[0][2].x) + __popcll(C0.y ^ wb[0][2].y);
        int m1 = __popcll(A1.x ^ wb[1][0].x) + __popcll(A1.y ^ wb[1][0].y)
               + __popcll(B1.x ^ wb[1][1].x) + __popcll(B1.y ^ wb[1][1].y)
               + __popcll(C1.x ^ wb[1][2].x) + __popcll(C1.y ^ wb[1][2].y);
        int m2 = __popcll(A2.x ^ wb[2][0].x) + __popcll(A2.y ^ wb[2][0].y)
               + __popcll(B2.x ^ wb[2][1].x) + __popcll(B2.y ^ wb[2][1].y)
               + __popcll(C2.x ^ wb[2][2].x) + __popcll(C2.y ^ wb[2][2].y);
        int y = base0 - 2 * (m0 + m1 + m2);
        if (i == 0  && g == 0) y -= ccol0;   // w == 0
        if (i == 27 && g == 1) y -= ccol2;   // w == 55
        int rr = y > 0 ? y : 0;
        s1 += (unsigned)rr;
        s2 += (unsigned)__mul24(rr, rr);     // rr <= 1152 -> exact, full-rate
        if (STORE_R) rout[(size_t)i * CH] = (unsigned short)rr;
        A0 = B0; A1 = B1; A2 = B2;
        B0 = C0; B1 = C1; B2 = C2;
    }
    int slot = (blockIdx.x + blockIdx.y * HH) & (NSLOT - 1);
    atomicAdd(&accum[slot * 256 + c],       (unsigned long long)s1);
    atomicAdd(&accum[slot * 256 + 128 + c], (unsigned long long)s2);
}

// ---------------- finalize BN: scale/shift per channel ----------------
__global__ __launch_bounds__(128) void finalize_k(const unsigned long long* __restrict__ accum,
                                                  const float* __restrict__ gamma,
                                                  const float* __restrict__ beta,
                                                  float2* __restrict__ ss) {
    int c = threadIdx.x;
    unsigned long long s1 = 0, s2 = 0;
    #pragma unroll
    for (int s = 0; s < NSLOT; ++s) {
        s1 += accum[s * 256 + c];
        s2 += accum[s * 256 + 128 + c];
    }
    double N    = (double)NPIX;
    double mean = (double)s1 / N;
    double var  = (double)s2 / N - mean * mean;
    double rstd = 1.0 / sqrt(var + 1e-3);
    double sc   = (double)gamma[c] * rstd;
    float2 v;
    v.x = (float)sc;
    v.y = (float)((double)beta[c] - mean * sc);
    ss[c] = v;
}

// ---------------- streaming output: out = r*scale + shift + x ----------------
__global__ __launch_bounds__(256) void out_stream_k(const unsigned short* __restrict__ rb,
                                                    const float2* __restrict__ ss,
                                                    const float* __restrict__ x,
                                                    float* __restrict__ out) {
    int idx4 = blockIdx.x * 256 + threadIdx.x;     // grid covers NPIX*CH/4 exactly
    int c4 = idx4 & (CH / 4 - 1);
    ushort4 r = ((const ushort4*)rb)[idx4];
    float4 xv = ((const float4*)x)[idx4];
    float2 s0 = ss[c4 * 4 + 0], s1 = ss[c4 * 4 + 1];
    float2 s2 = ss[c4 * 4 + 2], s3 = ss[c4 * 4 + 3];
    float4 o;
    o.x = fmaf((float)r.x, s0.x, s0.y + xv.x);
    o.y = fmaf((float)r.y, s1.x, s1.y + xv.y);
    o.z = fmaf((float)r.z, s2.x, s2.y + xv.z);
    o.w = fmaf((float)r.w, s3.x, s3.y + xv.w);
    ((float4*)out)[idx4] = o;
}

extern "C" void kernel_launch(void* const* d_in, const int* in_sizes, int n_in,
                              void* d_out, int out_size, void* d_ws, size_t ws_size,
                              hipStream_t stream) {
    const float* x     = (const float*)d_in[0];
    const float* Wt    = (const float*)d_in[1];
    const float* gamma = (const float*)d_in[2];
    const float* beta  = (const float*)d_in[3];
    float* out = (float*)d_out;

    char* ws = (char*)d_ws;
    const size_t XBP_BYTES = (size_t)BB * PROW * sizeof(U2);        // 1,722,368
    U2* xbp = (U2*)ws;
    U2* wb  = (U2*)(ws + 1722368);                                  // 18,432 B
    unsigned long long* accum = (unsigned long long*)(ws + 1740800);// 65,536 B
    float2* ss = (float2*)(ws + 1806336);                           // 1,024 B
    unsigned short* rb = (unsigned short*)(ws + 1807360);           // 25,690,112 B

    hipMemsetAsync(xbp, 0, XBP_BYTES, stream);                      // zero padding
    hipLaunchKernelGGL(pack_x_k, dim3(NPIX / 4), dim3(256), 0, stream, x, xbp);
    hipLaunchKernelGGL(pack_w_k, dim3(9),        dim3(128), 0, stream, Wt, wb, accum);
    hipLaunchKernelGGL(conv_stats_k<true>, dim3(HH, BB), dim3(256), 0, stream,
                       xbp, wb, accum, rb);
    hipLaunchKernelGGL(finalize_k, dim3(1), dim3(128), 0, stream, accum, gamma, beta, ss);
    hipLaunchKernelGGL(out_stream_k, dim3(NPIX * CH / 4 / 256), dim3(256), 0, stream,
                       rb, (const float2*)ss, x, out);
}